// Round 1
// baseline (180.437 us; speedup 1.0000x reference)
//
#include <hip/hip_runtime.h>
#include <hip/hip_bf16.h>
#include <stdint.h>

typedef uint32_t u32;
typedef uint64_t u64;
typedef __bf16 bf16x8 __attribute__((ext_vector_type(8)));
typedef float f32x4 __attribute__((ext_vector_type(4)));
typedef u32 u32x4 __attribute__((ext_vector_type(4)));

#define NB 8
#define NN 2048
#define DIN 256
#define DOUT 256
#define NR 4
#define KTOT (NN * NR)  // 8192

// ws layout
#define XW_BYTES   (NB * DOUT * KTOT * 2)          // 33,554,432
#define PART_BYTES (NB * NN * DOUT * 4)            // 16,777,216
#define WT_BYTES   (NR * DIN * DOUT * 2)           // 524,288

__device__ __forceinline__ ushort f2bf(float f) {
  union { float f; u32 u; } c; c.f = f;
  return (ushort)((c.u + 0x7FFFu + ((c.u >> 16) & 1u)) >> 16);
}

__device__ __forceinline__ void gload_lds16(const void* g, void* l) {
  __builtin_amdgcn_global_load_lds(
      (const __attribute__((address_space(1))) u32*)g,
      (__attribute__((address_space(3))) u32*)l, 16, 0, 0);
}

// ---------------- kernel 0: wT[r][o][d] = bf16(w[r][d][o]) ----------------
__global__ void k0_wT(const float* __restrict__ w, ushort* __restrict__ wT) {
  int i = blockIdx.x * 256 + threadIdx.x;   // 262144 total
  int o = i & 255, d = (i >> 8) & 255, r = i >> 16;
  wT[(r * DOUT + o) * DIN + d] = f2bf(w[i]);
}

// ---------------- kernel 1: xwT[b][o][m*4+r] = bf16(x[b,m,:]@W[r][:,o]) ----
// grid 512: b(8) x mc(32, m-tile 64) x ot(2, o-tile 128). 512 thr = 8 waves
// wave = (r = w>>1, oh = w&1): computes C_r[64 m][64 o], 4x4 frags 16x16x32.
__global__ __launch_bounds__(512) void k1_xw(const float* __restrict__ x,
                                             const ushort* __restrict__ wT,
                                             ushort* __restrict__ xwT) {
  __shared__ char smem[65536];
  ushort* As = (ushort*)smem;           // [64 m][32 d]
  ushort* Bs = (ushort*)(smem + 4096);  // [4 r][128 o][32 d]
  const int t = threadIdx.x, l = t & 63, w = t >> 6;
  const int r = w >> 1, oh = w & 1;
  const int blk = blockIdx.x;
  const int b = blk >> 6, rest = blk & 63, mc = rest >> 1, ot = rest & 1;

  f32x4 acc[4][4] = {};
  const int arow = t >> 3, adc = (t & 7) << 2;
  const float* xg = x + ((size_t)(b * NN + mc * 64 + arow) * DIN + adc);

  for (int s = 0; s < 8; ++s) {
    const int d0 = s * 32;
    // A stage: x f32 -> bf16
    float4 xv = *(const float4*)(xg + d0);
    ushort4 a4;
    a4.x = f2bf(xv.x); a4.y = f2bf(xv.y); a4.z = f2bf(xv.z); a4.w = f2bf(xv.w);
    *(ushort4*)(As + arow * 32 + adc) = a4;
    // B stage: wT panels, async
#pragma unroll
    for (int i = 0; i < 4; ++i) {
      int off = i * 4096 + t * 8;                 // element offset in Bs
      int rr = off >> 12, rem = off & 4095, o = rem >> 5, dd = rem & 31;
      const ushort* src = wT + ((size_t)(rr * DOUT + ot * 128 + o) * DIN + d0 + dd);
      gload_lds16(src, Bs + off);
    }
    __syncthreads();
    bf16x8 af[4];
#pragma unroll
    for (int fm = 0; fm < 4; ++fm)
      af[fm] = *(const bf16x8*)(As + (fm * 16 + (l & 15)) * 32 + (l >> 4) * 8);
#pragma unroll
    for (int fo = 0; fo < 4; ++fo) {
      bf16x8 bf = *(const bf16x8*)(Bs + (size_t)(r * 128 + oh * 64 + fo * 16 + (l & 15)) * 32 + (l >> 4) * 8);
#pragma unroll
      for (int fm = 0; fm < 4; ++fm)
        acc[fm][fo] = __builtin_amdgcn_mfma_f32_16x16x32_bf16(af[fm], bf, acc[fm][fo], 0, 0, 0);
    }
    __syncthreads();
  }
  // repack through LDS for coalesced interleaved stores: Cs[128 o][256 kp]
  ushort* Cs = (ushort*)smem;
#pragma unroll
  for (int fm = 0; fm < 4; ++fm)
#pragma unroll
    for (int fo = 0; fo < 4; ++fo)
#pragma unroll
      for (int j = 0; j < 4; ++j) {
        int o_loc = oh * 64 + fo * 16 + (l & 15);
        int ml = fm * 16 + (l >> 4) * 4 + j;
        Cs[o_loc * 256 + ml * 4 + r] = f2bf(acc[fm][fo][j]);
      }
  __syncthreads();
#pragma unroll
  for (int i = 0; i < 8; ++i) {
    int el = (i * 512 + t) * 8;
    int o_loc = el >> 8, kp = el & 255;
    *(uint4*)(xwT + (size_t)(b * DOUT + ot * 128 + o_loc) * KTOT + mc * 256 + kp) =
        *(const uint4*)(Cs + el);
  }
}

// ---------------- kernel 2: main one-hot GEMM ----------------
// grid 512: b(8) x nt(16, n-tile 128) x ot(2, o-tile 128) x ks(2, K-split).
// 256 thr = 4 waves (2x2), wave = 64x64, 4x4 frags, BK=64 (16 m x 4 r).
__global__ __launch_bounds__(256, 2) void k2_main(const int* __restrict__ rel,
                                                  const ushort* __restrict__ xwT,
                                                  float* __restrict__ out,
                                                  float* __restrict__ part) {
  __shared__ char smem[32768];
  ushort* As = (ushort*)smem;            // [128 n][64 k]
  ushort* Bs = (ushort*)(smem + 16384);  // [128 o][64 k]
  const int t = threadIdx.x, l = t & 63, w = t >> 6;
  const int wr = w >> 1, wc = w & 1;
  const int blk = blockIdx.x;
  const int b = blk >> 6, rest = blk & 63;
  const int nt = rest >> 2, ot = (rest >> 1) & 1, ks = rest & 1;

  f32x4 acc[4][4] = {};
  const int arow = t >> 1, ami = (t & 1) << 3;
  const int* relg = rel + ((size_t)(b * NN + nt * 128 + arow) * NN + ks * 1024 + ami);
  const ushort* xwb = xwT + (size_t)(b * DOUT + ot * 128) * KTOT + ks * 4096;

  for (int s = 0; s < 64; ++s) {
    // A stage: 8 relation ints -> one-hot bf16 (k = m*4 + r)
    int4 v0 = *(const int4*)(relg + s * 16);
    int4 v1 = *(const int4*)(relg + s * 16 + 4);
    ushort* ap = As + arow * 64 + ami * 4;
    int vv[8] = {v0.x, v0.y, v0.z, v0.w, v1.x, v1.y, v1.z, v1.w};
#pragma unroll
    for (int p = 0; p < 4; ++p) {
      int va = vv[2 * p], vb = vv[2 * p + 1];
      u32 sa = ((u32)(va - 1) & 3u) * 16u;
      u32 sb = ((u32)(vb - 1) & 3u) * 16u;
      u64 ha = va ? (0x3F80ull << sa) : 0ull;
      u64 hb = vb ? (0x3F80ull << sb) : 0ull;
      u32x4 e = {(u32)ha, (u32)(ha >> 32), (u32)hb, (u32)(hb >> 32)};
      *(u32x4*)(ap + p * 8) = e;
    }
    // B stage: xwT rows, async direct-to-LDS
#pragma unroll
    for (int i = 0; i < 4; ++i) {
      int off = i * 2048 + t * 8;
      int o = off >> 6, kd = off & 63;
      gload_lds16(xwb + (size_t)o * KTOT + s * 64 + kd, Bs + off);
    }
    __syncthreads();
#pragma unroll
    for (int kk = 0; kk < 2; ++kk) {
      bf16x8 af[4], bfv[4];
#pragma unroll
      for (int fm = 0; fm < 4; ++fm)
        af[fm] = *(const bf16x8*)(As + (wr * 64 + fm * 16 + (l & 15)) * 64 + kk * 32 + (l >> 4) * 8);
#pragma unroll
      for (int fo = 0; fo < 4; ++fo)
        bfv[fo] = *(const bf16x8*)(Bs + (wc * 64 + fo * 16 + (l & 15)) * 64 + kk * 32 + (l >> 4) * 8);
#pragma unroll
      for (int fm = 0; fm < 4; ++fm)
#pragma unroll
        for (int fo = 0; fo < 4; ++fo)
          acc[fm][fo] = __builtin_amdgcn_mfma_f32_16x16x32_bf16(af[fm], bfv[fo], acc[fm][fo], 0, 0, 0);
    }
    __syncthreads();
  }
  float* dst = ks ? part : out;
#pragma unroll
  for (int fm = 0; fm < 4; ++fm)
#pragma unroll
    for (int fo = 0; fo < 4; ++fo) {
      int n = nt * 128 + wr * 64 + fm * 16 + (l >> 4) * 4;
      int o = ot * 128 + wc * 64 + fo * 16 + (l & 15);
#pragma unroll
      for (int j = 0; j < 4; ++j)
        dst[(size_t)(b * NN + n + j) * DOUT + o] = acc[fm][fo][j];
    }
}

// ---------------- kernel 3: out = out(ks0) + part(ks1) + bias --------------
__global__ void k3_add(float* __restrict__ out, const float* __restrict__ part,
                       const float* __restrict__ bias) {
  int i = blockIdx.x * 256 + threadIdx.x;  // float4 index, 1048576 total
  float4 o = ((const float4*)out)[i];
  float4 p = ((const float4*)part)[i];
  float4 bv = ((const float4*)bias)[i & 63];
  float4 rr;
  rr.x = o.x + p.x + bv.x;
  rr.y = o.y + p.y + bv.y;
  rr.z = o.z + p.z + bv.z;
  rr.w = o.w + p.w + bv.w;
  ((float4*)out)[i] = rr;
}

extern "C" void kernel_launch(void* const* d_in, const int* in_sizes, int n_in,
                              void* d_out, int out_size, void* d_ws, size_t ws_size,
                              hipStream_t stream) {
  const float* x = (const float*)d_in[0];
  // d_in[1] = adj (unused by the module)
  const int* rel = (const int*)d_in[2];
  const float* wgt = (const float*)d_in[3];
  const float* bias = (const float*)d_in[4];
  float* out = (float*)d_out;
  char* ws = (char*)d_ws;

  ushort* xwT = (ushort*)ws;                                 // 32 MiB
  float* part = (float*)(ws + XW_BYTES);                     // 16 MiB
  ushort* wT = (ushort*)(ws + XW_BYTES + PART_BYTES);        // 0.5 MiB

  k0_wT<<<1024, 256, 0, stream>>>(wgt, wT);
  k1_xw<<<512, 512, 0, stream>>>(x, wT, xwT);
  k2_main<<<512, 256, 0, stream>>>(rel, xwT, out, part);
  k3_add<<<4096, 256, 0, stream>>>(out, part, bias);
}

// Round 2
// 126.095 us; speedup vs baseline: 1.4310x; 1.4310x over previous
//
#include <hip/hip_runtime.h>
#include <hip/hip_bf16.h>
#include <stdint.h>

typedef uint32_t u32;
typedef uint64_t u64;
typedef __bf16 bf16x8 __attribute__((ext_vector_type(8)));
typedef float f32x4 __attribute__((ext_vector_type(4)));
typedef u32 u32x4 __attribute__((ext_vector_type(4)));

#define NB 8
#define NN 2048
#define DIN 256
#define DOUT 256
#define NR 4
#define KTOT (NN * NR)  // 8192

// ws layout
#define XW_BYTES   (NB * DOUT * KTOT * 2)          // 33,554,432
#define PART_BYTES (NB * NN * DOUT * 4)            // 16,777,216
#define WT_BYTES   (NR * DIN * DOUT * 2)           // 524,288

__device__ __forceinline__ ushort f2bf(float f) {
  union { float f; u32 u; } c; c.f = f;
  return (ushort)((c.u + 0x7FFFu + ((c.u >> 16) & 1u)) >> 16);
}

__device__ __forceinline__ void gload_lds16(const void* g, void* l) {
  __builtin_amdgcn_global_load_lds(
      (const __attribute__((address_space(1))) u32*)g,
      (__attribute__((address_space(3))) u32*)l, 16, 0, 0);
}

// ---------------- kernel 0: wT[r][o][d] = bf16(w[r][d][o]) ----------------
__global__ void k0_wT(const float* __restrict__ w, ushort* __restrict__ wT) {
  int i = blockIdx.x * 256 + threadIdx.x;   // 262144 total
  int o = i & 255, d = (i >> 8) & 255, r = i >> 16;
  wT[(r * DOUT + o) * DIN + d] = f2bf(w[i]);
}

// ---------------- kernel 1: xwT[b][o][m*4+r] = bf16(x[b,m,:]@W[r][:,o]) ----
__global__ __launch_bounds__(512) void k1_xw(const float* __restrict__ x,
                                             const ushort* __restrict__ wT,
                                             ushort* __restrict__ xwT) {
  __shared__ char smem[65536];
  ushort* As = (ushort*)smem;           // [64 m][32 d]
  ushort* Bs = (ushort*)(smem + 4096);  // [4 r][128 o][32 d]
  const int t = threadIdx.x, l = t & 63, w = t >> 6;
  const int r = w >> 1, oh = w & 1;
  const int blk = blockIdx.x;
  const int b = blk >> 6, rest = blk & 63, mc = rest >> 1, ot = rest & 1;

  f32x4 acc[4][4] = {};
  const int arow = t >> 3, adc = (t & 7) << 2;
  const float* xg = x + ((size_t)(b * NN + mc * 64 + arow) * DIN + adc);

  for (int s = 0; s < 8; ++s) {
    const int d0 = s * 32;
    float4 xv = *(const float4*)(xg + d0);
    ushort4 a4;
    a4.x = f2bf(xv.x); a4.y = f2bf(xv.y); a4.z = f2bf(xv.z); a4.w = f2bf(xv.w);
    *(ushort4*)(As + arow * 32 + adc) = a4;
#pragma unroll
    for (int i = 0; i < 4; ++i) {
      int off = i * 4096 + t * 8;
      int rr = off >> 12, rem = off & 4095, o = rem >> 5, dd = rem & 31;
      const ushort* src = wT + ((size_t)(rr * DOUT + ot * 128 + o) * DIN + d0 + dd);
      gload_lds16(src, Bs + off);
    }
    __syncthreads();
    bf16x8 af[4];
#pragma unroll
    for (int fm = 0; fm < 4; ++fm)
      af[fm] = *(const bf16x8*)(As + (fm * 16 + (l & 15)) * 32 + (l >> 4) * 8);
#pragma unroll
    for (int fo = 0; fo < 4; ++fo) {
      bf16x8 bf = *(const bf16x8*)(Bs + (size_t)(r * 128 + oh * 64 + fo * 16 + (l & 15)) * 32 + (l >> 4) * 8);
#pragma unroll
      for (int fm = 0; fm < 4; ++fm)
        acc[fm][fo] = __builtin_amdgcn_mfma_f32_16x16x32_bf16(af[fm], bf, acc[fm][fo], 0, 0, 0);
    }
    __syncthreads();
  }
  ushort* Cs = (ushort*)smem;
#pragma unroll
  for (int fm = 0; fm < 4; ++fm)
#pragma unroll
    for (int fo = 0; fo < 4; ++fo)
#pragma unroll
      for (int j = 0; j < 4; ++j) {
        int o_loc = oh * 64 + fo * 16 + (l & 15);
        int ml = fm * 16 + (l >> 4) * 4 + j;
        Cs[o_loc * 256 + ml * 4 + r] = f2bf(acc[fm][fo][j]);
      }
  __syncthreads();
#pragma unroll
  for (int i = 0; i < 8; ++i) {
    int el = (i * 512 + t) * 8;
    int o_loc = el >> 8, kp = el & 255;
    *(uint4*)(xwT + (size_t)(b * DOUT + ot * 128 + o_loc) * KTOT + mc * 256 + kp) =
        *(const uint4*)(Cs + el);
  }
}

// ---------------- kernel 2: main one-hot GEMM (2-phase dbuf + T2 swizzle) --
// grid 512 logical: b(3).nt(4).ks(1).ot(1), XCD-swizzled so ot-pairs co-XCD.
// 256 thr = 4 waves (2x2), wave = 64x64, 4x4 frags of 16x16x32, BK=64.
// LDS: A dbuf 2x16KB (reg-staged, XOR-swizzled) + B dbuf 2x16KB
// (global_load_lds linear dest, pre-swizzled global source).
__global__ __launch_bounds__(256, 2) void k2_main(const int* __restrict__ rel,
                                                  const ushort* __restrict__ xwT,
                                                  float* __restrict__ out,
                                                  float* __restrict__ part) {
  __shared__ char smem[65536];
  const int t = threadIdx.x, l = t & 63, w = t >> 6;
  const int wr = w >> 1, wc = w & 1;
  // XCD-aware bijective swizzle: 512 % 8 == 0
  const int logical = (blockIdx.x & 7) * 64 + (blockIdx.x >> 3);
  const int b = logical >> 6;
  const int nt = (logical >> 2) & 15;
  const int ks = (logical >> 1) & 1;
  const int ot = logical & 1;

  f32x4 acc[4][4] = {};
  const int arow = t >> 1, half = t & 1;
  const int* relg = rel + ((size_t)(b * NN + nt * 128 + arow) * NN + ks * 1024 + half * 8);
  const ushort* xwb = xwT + (size_t)(b * DOUT + ot * 128) * KTOT + ks * 4096;

  // B stage source-swizzle column (constant per thread): involution with read
  const int kd = (((t & 7) ^ ((t >> 3) & 7)) << 3);
  const int brow = t >> 3;  // + i*32 per instruction

  const int aswz = (arow & 7) << 4;

#define STAGE_B(sidx, bufoff)                                                  \
  {                                                                            \
    _Pragma("unroll") for (int i = 0; i < 4; ++i) {                            \
      int o = i * 32 + brow;                                                   \
      gload_lds16(xwb + (size_t)o * KTOT + (sidx) * 64 + kd,                   \
                  smem + (bufoff) + i * 4096 + t * 16);                        \
    }                                                                          \
  }

#define EXPAND_A(bufoff, v0, v1)                                               \
  {                                                                            \
    char* rowp = smem + (bufoff) + arow * 128;                                 \
    int vv[8] = {v0.x, v0.y, v0.z, v0.w, v1.x, v1.y, v1.z, v1.w};              \
    _Pragma("unroll") for (int p = 0; p < 4; ++p) {                            \
      int va = vv[2 * p], vb = vv[2 * p + 1];                                  \
      u32 sa = ((u32)(va - 1) & 3u) * 16u;                                     \
      u32 sb = ((u32)(vb - 1) & 3u) * 16u;                                     \
      u64 ha = va ? (0x3F80ull << sa) : 0ull;                                  \
      u64 hb = vb ? (0x3F80ull << sb) : 0ull;                                  \
      u32x4 e = {(u32)ha, (u32)(ha >> 32), (u32)hb, (u32)(hb >> 32)};          \
      *(u32x4*)(rowp + (((half * 64 + p * 16)) ^ aswz)) = e;                   \
    }                                                                          \
  }

  // prologue: stage step 0 into buffers 0
  STAGE_B(0, 32768);
  {
    int4 p0 = *(const int4*)(relg);
    int4 p1 = *(const int4*)(relg + 4);
    EXPAND_A(0, p0, p1);
  }
  __syncthreads();

  const int fr = l & 15, fq = l >> 4;
  const int rswz = (fr & 7) << 4;

  for (int s = 0; s < 64; ++s) {
    const int cur = (s & 1) * 16384;
    const int nxt = ((s + 1) & 1) * 16384;
    int4 r0, r1;
    if (s < 63) {
      STAGE_B(s + 1, 32768 + nxt);
      r0 = *(const int4*)(relg + (s + 1) * 16);
      r1 = *(const int4*)(relg + (s + 1) * 16 + 4);
    }
    const char* Ac = smem + cur;
    const char* Bc = smem + 32768 + cur;
#pragma unroll
    for (int kk = 0; kk < 2; ++kk) {
      bf16x8 af[4], bfv[4];
      const int colb = (kk * 64 + fq * 16) ^ rswz;
#pragma unroll
      for (int fm = 0; fm < 4; ++fm)
        af[fm] = *(const bf16x8*)(Ac + (wr * 64 + fm * 16 + fr) * 128 + colb);
#pragma unroll
      for (int fo = 0; fo < 4; ++fo)
        bfv[fo] = *(const bf16x8*)(Bc + (wc * 64 + fo * 16 + fr) * 128 + colb);
#pragma unroll
      for (int fm = 0; fm < 4; ++fm)
#pragma unroll
        for (int fo = 0; fo < 4; ++fo)
          acc[fm][fo] = __builtin_amdgcn_mfma_f32_16x16x32_bf16(af[fm], bfv[fo], acc[fm][fo], 0, 0, 0);
    }
    if (s < 63) EXPAND_A(nxt, r0, r1);
    __syncthreads();
  }

  float* dst = ks ? part : out;
#pragma unroll
  for (int fm = 0; fm < 4; ++fm)
#pragma unroll
    for (int fo = 0; fo < 4; ++fo) {
      int n = nt * 128 + wr * 64 + fm * 16 + fq * 4;
      int o = ot * 128 + wc * 64 + fo * 16 + fr;
#pragma unroll
      for (int j = 0; j < 4; ++j)
        dst[(size_t)(b * NN + n + j) * DOUT + o] = acc[fm][fo][j];
    }
#undef STAGE_B
#undef EXPAND_A
}

// ---------------- kernel 3: out = out(ks0) + part(ks1) + bias --------------
__global__ void k3_add(float* __restrict__ out, const float* __restrict__ part,
                       const float* __restrict__ bias) {
  int i = blockIdx.x * 256 + threadIdx.x;  // float4 index, 1048576 total
  float4 o = ((const float4*)out)[i];
  float4 p = ((const float4*)part)[i];
  float4 bv = ((const float4*)bias)[i & 63];
  float4 rr;
  rr.x = o.x + p.x + bv.x;
  rr.y = o.y + p.y + bv.y;
  rr.z = o.z + p.z + bv.z;
  rr.w = o.w + p.w + bv.w;
  ((float4*)out)[i] = rr;
}

extern "C" void kernel_launch(void* const* d_in, const int* in_sizes, int n_in,
                              void* d_out, int out_size, void* d_ws, size_t ws_size,
                              hipStream_t stream) {
  const float* x = (const float*)d_in[0];
  const int* rel = (const int*)d_in[2];
  const float* wgt = (const float*)d_in[3];
  const float* bias = (const float*)d_in[4];
  float* out = (float*)d_out;
  char* ws = (char*)d_ws;

  ushort* xwT = (ushort*)ws;                                 // 32 MiB
  float* part = (float*)(ws + XW_BYTES);                     // 16 MiB
  ushort* wT = (ushort*)(ws + XW_BYTES + PART_BYTES);        // 0.5 MiB

  k0_wT<<<1024, 256, 0, stream>>>(wgt, wT);
  k1_xw<<<512, 512, 0, stream>>>(x, wT, xwT);
  k2_main<<<512, 256, 0, stream>>>(rel, xwT, out, part);
  k3_add<<<4096, 256, 0, stream>>>(out, part, bias);
}